// Round 1
// baseline (169.917 us; speedup 1.0000x reference)
//
#include <hip/hip_runtime.h>
#include <stdint.h>

#define N_NODES 100000
#define KNBR 16
#define DIM 256
#define DOUT 256
#define ALPHA 0.2f
#define BM 32            // nodes per block in the fused kernel

typedef __attribute__((ext_vector_type(8))) short bf16x8;
typedef __attribute__((ext_vector_type(4))) float f32x4;
typedef unsigned short u16;
typedef unsigned int u32;

static __device__ __forceinline__ u16 f2bf(float f) {
  u32 u = __builtin_bit_cast(u32, f);
  u += 0x7fffu + ((u >> 16) & 1u);   // round-to-nearest-even
  return (u16)(u >> 16);
}
static __device__ __forceinline__ float bf2f(u16 s) {
  return __builtin_bit_cast(float, ((u32)s) << 16);
}

// Kernel 1: (a) convert h fp32 -> bf16 into ws, (b) pre-swizzle W into
// MFMA B-fragment order: frag(ks, ct): lane l, elem i = W[ks*32+(l>>4)*8+i][ct*16+(l&15)]
__global__ __launch_bounds__(256) void prep_kernel(const float* __restrict__ h,
                                                   const float* __restrict__ W,
                                                   u16* __restrict__ hb,
                                                   u16* __restrict__ Wb,
                                                   int hBlocks) {
  const int bid = blockIdx.x;
  if (bid < hBlocks) {
    const size_t base = (size_t)bid * 2048 + (size_t)threadIdx.x * 8;
    const float4 v0 = *(const float4*)(h + base);
    const float4 v1 = *(const float4*)(h + base + 4);
    uint4 o;
    o.x = (u32)f2bf(v0.x) | ((u32)f2bf(v0.y) << 16);
    o.y = (u32)f2bf(v0.z) | ((u32)f2bf(v0.w) << 16);
    o.z = (u32)f2bf(v1.x) | ((u32)f2bf(v1.y) << 16);
    o.w = (u32)f2bf(v1.z) | ((u32)f2bf(v1.w) << 16);
    *(uint4*)(hb + base) = o;
  } else {
    const int t = (bid - hBlocks) * 256 + threadIdx.x;  // 0..8191
    const int l = t & 63;
    const int ct = (t >> 6) & 15;
    const int ks = t >> 10;
    const int colbase = ct * 16 + (l & 15);
    const int k0 = ks * 32 + (l >> 4) * 8;
    u32 wq[4];
#pragma unroll
    for (int q = 0; q < 4; ++q) {
      const u16 b0 = f2bf(W[(k0 + 2 * q) * 256 + colbase]);
      const u16 b1 = f2bf(W[(k0 + 2 * q + 1) * 256 + colbase]);
      wq[q] = (u32)b0 | ((u32)b1 << 16);
    }
    uint4 o = {wq[0], wq[1], wq[2], wq[3]};
    *(uint4*)(Wb + (size_t)t * 8) = o;
  }
}

// Kernel 2: fused gather-mean -> bf16 MFMA GEMM -> leaky -> L2-normalize -> store
template <bool USE_HB>
__global__ __launch_bounds__(256, 4) void sage_kernel(
    const float* __restrict__ h, const u16* __restrict__ hb,
    const int* __restrict__ nbr, const u16* __restrict__ Wb,
    float* __restrict__ out) {
  __shared__ __align__(16) u16 aggS[BM * 256];   // 16 KB, XOR-swizzled rows
  __shared__ int nbrS[BM * KNBR];                // 2 KB
  __shared__ float rowpart[4][BM];
  __shared__ float invS[BM];

  const int tid = threadIdx.x;
  const int blk = blockIdx.x;

  nbrS[tid] = nbr[blk * (BM * KNBR) + tid];
  nbrS[tid + 256] = nbr[blk * (BM * KNBR) + 256 + tid];
  __syncthreads();

  // ---- phase 1: gather + mean, write bf16 agg tile to LDS (swizzled) ----
  {
    const int chunk = tid & 31;     // which 8-dim chunk
    const int dim0 = chunk * 8;
    const int nsub = tid >> 5;      // 0..7
#pragma unroll
    for (int p = 0; p < 4; ++p) {
      const int n = p * 8 + nsub;
      const int node = blk * BM + n;
      float acc[8];
#pragma unroll
      for (int q = 0; q < 8; ++q) acc[q] = 0.f;
#pragma unroll
      for (int j = 0; j < 17; ++j) {
        const int row = (j == 0) ? node : nbrS[n * KNBR + (j - 1)];
        if (USE_HB) {
          const uint4 v = *(const uint4*)(hb + (size_t)row * 256 + dim0);
          acc[0] += bf2f((u16)(v.x & 0xffff)); acc[1] += bf2f((u16)(v.x >> 16));
          acc[2] += bf2f((u16)(v.y & 0xffff)); acc[3] += bf2f((u16)(v.y >> 16));
          acc[4] += bf2f((u16)(v.z & 0xffff)); acc[5] += bf2f((u16)(v.z >> 16));
          acc[6] += bf2f((u16)(v.w & 0xffff)); acc[7] += bf2f((u16)(v.w >> 16));
        } else {
          const float4* fp = (const float4*)(h + (size_t)row * 256 + dim0);
          const float4 a = fp[0], b = fp[1];
          acc[0] += a.x; acc[1] += a.y; acc[2] += a.z; acc[3] += a.w;
          acc[4] += b.x; acc[5] += b.y; acc[6] += b.z; acc[7] += b.w;
        }
      }
      const float s = 1.0f / 17.0f;
      uint4 o;
      o.x = (u32)f2bf(acc[0] * s) | ((u32)f2bf(acc[1] * s) << 16);
      o.y = (u32)f2bf(acc[2] * s) | ((u32)f2bf(acc[3] * s) << 16);
      o.z = (u32)f2bf(acc[4] * s) | ((u32)f2bf(acc[5] * s) << 16);
      o.w = (u32)f2bf(acc[6] * s) | ((u32)f2bf(acc[7] * s) << 16);
      *(uint4*)((char*)aggS + n * 512 + ((dim0 * 2) ^ ((n & 7) << 4))) = o;
    }
  }
  __syncthreads();

  // ---- phase 2: MFMA GEMM  (A = agg[32x256] from LDS, B = W frags from L2) ----
  const int l = tid & 63, wv = tid >> 6;
  const int l15 = l & 15, lg = l >> 4;
  f32x4 acc[2][4] = {};
  const uint4* wbL = ((const uint4*)Wb) + (size_t)(wv * 4) * 64 + l;
  const char* aggB = (const char*)aggS;
  const int rb0 = l15 * 512;
  const int xm = (l15 & 7) << 4;
#pragma unroll 2
  for (int ks = 0; ks < 8; ++ks) {
    const int offk = ((ks * 64) + lg * 16) ^ xm;
    const bf16x8 a0 = *(const bf16x8*)(aggB + rb0 + offk);
    const bf16x8 a1 = *(const bf16x8*)(aggB + rb0 + 8192 + offk);
#pragma unroll
    for (int c = 0; c < 4; ++c) {
      const uint4 bw = wbL[ks * 1024 + c * 64];
      const bf16x8 b = __builtin_bit_cast(bf16x8, bw);
      acc[0][c] = __builtin_amdgcn_mfma_f32_16x16x32_bf16(a0, b, acc[0][c], 0, 0, 0);
      acc[1][c] = __builtin_amdgcn_mfma_f32_16x16x32_bf16(a1, b, acc[1][c], 0, 0, 0);
    }
  }

  // ---- phase 3: leaky relu + row sum-of-squares (cross-wave via LDS) ----
#pragma unroll
  for (int rt = 0; rt < 2; ++rt) {
#pragma unroll
    for (int j = 0; j < 4; ++j) {
      float s = 0.f;
#pragma unroll
      for (int c = 0; c < 4; ++c) {
        float v = acc[rt][c][j];
        v = (v >= 0.f) ? v : ALPHA * v;
        acc[rt][c][j] = v;
        s += v * v;
      }
      s += __shfl_xor(s, 1); s += __shfl_xor(s, 2);
      s += __shfl_xor(s, 4); s += __shfl_xor(s, 8);
      if (l15 == 0) rowpart[wv][rt * 16 + lg * 4 + j] = s;
    }
  }
  __syncthreads();
  if (tid < BM) {
    const float t = rowpart[0][tid] + rowpart[1][tid] + rowpart[2][tid] + rowpart[3][tid];
    invS[tid] = 1.0f / fmaxf(sqrtf(t), 1e-12f);
  }
  __syncthreads();

  // ---- phase 4: normalize + store ----
  float* op = out + (size_t)blk * (BM * 256) + wv * 64;
#pragma unroll
  for (int rt = 0; rt < 2; ++rt) {
#pragma unroll
    for (int j = 0; j < 4; ++j) {
      const int r = rt * 16 + lg * 4 + j;
      const float iv = invS[r];
#pragma unroll
      for (int c = 0; c < 4; ++c)
        op[(size_t)r * 256 + c * 16 + l15] = acc[rt][c][j] * iv;
    }
  }
}

extern "C" void kernel_launch(void* const* d_in, const int* in_sizes, int n_in,
                              void* d_out, int out_size, void* d_ws, size_t ws_size,
                              hipStream_t stream) {
  const float* h = (const float*)d_in[0];
  const int* nbr = (const int*)d_in[1];
  const float* W = (const float*)d_in[2];
  float* out = (float*)d_out;

  u16* Wb = (u16*)d_ws;                              // 128 KB fragment-ordered W
  u16* hb = (u16*)((char*)d_ws + 131072);            // 51.2 MB bf16 copy of h
  const size_t needHB = 131072 + (size_t)N_NODES * DIM * 2;
  const bool useHB = ws_size >= needHB;

  const int hBlocks = useHB ? (N_NODES * DIM / 2048) : 0;  // 12500
  prep_kernel<<<hBlocks + 32, 256, 0, stream>>>(h, W, hb, Wb, hBlocks);

  if (useHB)
    sage_kernel<true><<<N_NODES / BM, 256, 0, stream>>>(h, hb, nbr, Wb, out);
  else
    sage_kernel<false><<<N_NODES / BM, 256, 0, stream>>>(h, hb, nbr, Wb, out);
}